// Round 16
// baseline (1038.987 us; speedup 1.0000x reference)
//
#include <hip/hip_runtime.h>
#include <stdint.h>

#define NN 50000
#define DD 80
#define NE 800000
#define EDIM 16
#define PED 37
#define NG 256
#define NLAY 4
#define KZ 480
#define NOUT 240
#define MPAD 50048
#define NBLK (MPAD/64)
#define NB 196
#define KP 64
#define NPE (NLAY*DD)   // 320
#define EREC 32         // edge record: 32 ushorts = 64B
#define AVG_LD 1.4059212841460147f
#define S5 0.0031622776601683794f

typedef __bf16 bf16x8 __attribute__((ext_vector_type(8)));
typedef float f32x4 __attribute__((ext_vector_type(4)));

__device__ __forceinline__ unsigned short f2bf(float f){
  union { float f; unsigned u; } v; v.f = f;
  return (unsigned short)((v.u + 0x7fffu + ((v.u >> 16) & 1u)) >> 16);
}
__device__ __forceinline__ float bf2f(unsigned short u){
  union { unsigned u; float f; } v; v.u = ((unsigned)u) << 16; return v.f;
}
__device__ __forceinline__ unsigned packbf(float a, float b){
  return (unsigned)f2bf(a) | ((unsigned)f2bf(b) << 16);
}

// ---- fused init: hist, Z-pad=0 (uint4), wprep (4 layers), PEb bf16, pwT bf16 ----
#define R_HIST NE
#define R_ZP8  (((MPAD-NN)*KZ)/8)
#define R_WP   (NLAY*NOUT*KZ)
#define R_PEB  (MPAD*KP)
#define R_PWT  (NPE*KP)
#define R_TOT  (R_HIST + R_ZP8 + R_WP + R_PEB + R_PWT)

__global__ void k_init(const int* __restrict__ ei, int* deg, unsigned short* Z,
                       const float* __restrict__ conv_w, unsigned short* __restrict__ WcT,
                       const float* __restrict__ PE,
                       const float* __restrict__ pe_w, const float* __restrict__ pe_b,
                       unsigned short* __restrict__ PEb, unsigned short* __restrict__ pwT){
  int idx = blockIdx.x*blockDim.x + threadIdx.x;
  if(idx < R_HIST){ atomicAdd(&deg[ei[NE + idx]], 1); return; }
  int r1 = idx - R_HIST;
  if(r1 < R_ZP8){
    uint4* zp = (uint4*)(Z + (size_t)NN*KZ);
    zp[r1] = (uint4){0,0,0,0};
    return;
  }
  int r2 = r1 - R_ZP8;
  if(r2 < R_WP){
    int l = r2 / (NOUT*KZ);
    int k = r2 % (NOUT*KZ);
    int j = k / KZ;
    int r = k % KZ;
    int ks = j / DD, c = j % DD;
    const float* cw = conv_w + (size_t)l*2112*DD;
    float val = 0.0f;
    if(r < 384){
      int stat = r/96, m = r%96;
      val = cw[(size_t)(ks*704 + stat*176 + 80 + m)*DD + c];
    } else if(r < 464){
      int m = r - 384;
      int b = ks*704 + m;
      val = cw[(size_t)b*DD + c] + cw[(size_t)(b+176)*DD + c] + cw[(size_t)(b+352)*DD + c];
    } else if(r == 464){
      float s = 0.0f; int b = ks*704 + 528;
      for(int m=0;m<80;++m) s += cw[(size_t)(b+m)*DD + c];
      val = S5 * s;
    }
    WcT[(size_t)l*NOUT*KZ + k] = f2bf(val);
    return;
  }
  int r3 = r2 - R_WP;
  if(r3 < R_PEB){
    int i = r3 / KP, k = r3 % KP;
    float v = 0.0f;
    if(i < NN){
      if(k < PED) v = PE[(size_t)i*PED + k];
      else if(k == PED) v = 1.0f;
    }
    PEb[r3] = f2bf(v);
    return;
  }
  int r4 = r3 - R_PEB;
  if(r4 < R_PWT){
    int j = r4 / KP, k = r4 % KP;
    int l = j / DD, c = j % DD;
    float v = 0.0f;
    if(k < PED) v = pe_w[(size_t)(l*PED + k)*DD + c];
    else if(k == PED) v = pe_b[l*DD + c];
    pwT[r4] = f2bf(v);
  }
}

// PE-embedding GEMM
__global__ __launch_bounds__(256) void k_pegemm(
    const unsigned short* __restrict__ PEb, const unsigned short* __restrict__ pwT,
    const float* __restrict__ x0, unsigned short* __restrict__ pe_all,
    unsigned short* __restrict__ xpb){
  int tid = threadIdx.x;
  int wave = tid >> 6, lane = tid & 63;
  int r = lane & 15, q = lane >> 4;
  int m0 = blockIdx.x*64 + wave*16;
  const unsigned short* Ap = PEb + (size_t)(m0 + r)*KP + q*8;
  const unsigned short* Bp = pwT + (size_t)r*KP + q*8;
  f32x4 acc[20];
  #pragma unroll
  for(int i=0;i<20;++i) acc[i] = (f32x4){0.f,0.f,0.f,0.f};
  #pragma unroll
  for(int k0=0; k0<KP; k0+=32){
    bf16x8 a = *(const bf16x8*)(Ap + k0);
    #pragma unroll
    for(int ct=0; ct<20; ++ct){
      bf16x8 b = *(const bf16x8*)(Bp + (size_t)ct*16*KP + k0);
      acc[ct] = __builtin_amdgcn_mfma_f32_16x16x32_bf16(a, b, acc[ct], 0, 0, 0);
    }
  }
  #pragma unroll
  for(int rr=0; rr<4; ++rr){
    int grow = m0 + q*4 + rr;
    #pragma unroll
    for(int ct=0; ct<20; ++ct){
      int c = ct*16 + r;
      float v = acc[ct][rr];
      pe_all[(size_t)grow*NPE + c] = f2bf(v);
      if(c < DD && grow < NN)
        xpb[(size_t)grow*DD + c] = f2bf(x0[(size_t)grow*DD + c] + v);
    }
  }
}

// ---------------- CSR build ----------------
__global__ void k_scan1(const int* __restrict__ deg, int* bsum){
  __shared__ int red[256];
  int i = blockIdx.x*256 + threadIdx.x;
  int v = (i < NN) ? deg[i] : 0;
  red[threadIdx.x] = v; __syncthreads();
  for(int d=128; d>0; d>>=1){
    if(threadIdx.x < d) red[threadIdx.x] += red[threadIdx.x + d];
    __syncthreads();
  }
  if(threadIdx.x == 0) bsum[blockIdx.x] = red[0];
}

// merged scan: each block reduces bsum[0..blockIdx) itself, then local scan
__global__ void k_scan3(const int* __restrict__ deg, const int* __restrict__ bsum,
                        int* off, int* pos){
  __shared__ int s[256];
  __shared__ int base_sh;
  int t = threadIdx.x;
  int v = (t < blockIdx.x) ? bsum[t] : 0;   // NB=196 < 256
  s[t] = v; __syncthreads();
  for(int d=128; d>0; d>>=1){
    if(t < d) s[t] += s[t + d];
    __syncthreads();
  }
  if(t == 0) base_sh = s[0];
  __syncthreads();
  int base = base_sh;
  __syncthreads();
  int i = blockIdx.x*256 + t;
  int dv = (i < NN) ? deg[i] : 0;
  s[t] = dv; __syncthreads();
  for(int d=1; d<256; d<<=1){
    int u = (t >= d) ? s[t-d] : 0;
    __syncthreads();
    s[t] += u;
    __syncthreads();
  }
  int excl = s[t] - dv + base;
  if(i < NN){ off[i] = excl; pos[i] = excl; }
  if(blockIdx.x == NB-1 && t == 255) off[NN] = s[255] + base;
}

// fill CSR: one full 64B record per edge [16 bf16 ea | src int | pad]
__global__ void k_fill(const int* __restrict__ ei, const float* __restrict__ ea,
                       int* pos, unsigned short* __restrict__ erec){
  int e = blockIdx.x*blockDim.x + threadIdx.x;
  if(e >= NE) return;
  int t = ei[NE + e];
  int idx = atomicAdd(&pos[t], 1);
  const float4* s = (const float4*)(ea + (size_t)e*EDIM);
  float4 f0=s[0], f1=s[1], f2=s[2], f3=s[3];
  unsigned short tmp[32];
  tmp[0]=f2bf(f0.x); tmp[1]=f2bf(f0.y); tmp[2]=f2bf(f0.z); tmp[3]=f2bf(f0.w);
  tmp[4]=f2bf(f1.x); tmp[5]=f2bf(f1.y); tmp[6]=f2bf(f1.z); tmp[7]=f2bf(f1.w);
  tmp[8]=f2bf(f2.x); tmp[9]=f2bf(f2.y); tmp[10]=f2bf(f2.z); tmp[11]=f2bf(f2.w);
  tmp[12]=f2bf(f3.x); tmp[13]=f2bf(f3.y); tmp[14]=f2bf(f3.z); tmp[15]=f2bf(f3.w);
  *(int*)&tmp[16] = ei[e];
  *(int*)&tmp[18] = 0;
  *(uint4*)&tmp[20] = (uint4){0,0,0,0};
  *(uint4*)&tmp[28] = (uint4){0,0,0,0};
  uint4* d = (uint4*)(erec + (size_t)idx*EREC);
  d[0] = *(uint4*)&tmp[0];
  d[1] = *(uint4*)&tmp[8];
  d[2] = *(uint4*)&tmp[16];
  d[3] = *(uint4*)&tmp[24];
}

// ---------------- per-layer aggregation [R12-proven] ----------------
__global__ __launch_bounds__(256) void k_agg(
    const unsigned short* __restrict__ xpb, const unsigned short* __restrict__ erec,
    const int* __restrict__ off, unsigned short* __restrict__ Z,
    float2* __restrict__ sc){
  int g = blockIdx.x*4 + (threadIdx.x >> 6);
  if(g >= NN) return;
  int lane = threadIdx.x & 63;
  int h = lane >> 5, t = lane & 31;
  int lo = off[g], hi = off[g+1];
  int d = hi - lo;
  float s0=0,s1=0,s2=0,q0=0,q1=0,q2=0;
  const float INF = __builtin_huge_valf();
  float mn0=INF,mn1=INF,mn2=INF,mx0=-INF,mx1=-INF,mx2=-INF;

  auto edge = [&](int j){
    const unsigned short* er = erec + (size_t)j*EREC;
    int sr = *(const int*)(er + 16);
    const unsigned* xr32 = (const unsigned*)(xpb + (size_t)sr*DD);
    unsigned w = xr32[t];
    union {unsigned u; float f;} ua, ub;
    ua.u = w << 16; ub.u = w & 0xffff0000u;
    float v0 = ua.f, v1 = ub.f;
    unsigned short u2 = (t < 16) ? xpb[(size_t)sr*DD + 64 + t] : er[t - 16];
    float v2 = bf2f(u2);
    s0+=v0; q0+=v0*v0; mn0=fminf(mn0,v0); mx0=fmaxf(mx0,v0);
    s1+=v1; q1+=v1*v1; mn1=fminf(mn1,v1); mx1=fmaxf(mx1,v1);
    s2+=v2; q2+=v2*v2; mn2=fminf(mn2,v2); mx2=fmaxf(mx2,v2);
  };
  int j = lo + h;
  for(; j + 2 < hi; j += 4){ edge(j); edge(j+2); }
  if(j < hi) edge(j);

  s0 += __shfl_xor(s0,32,64); s1 += __shfl_xor(s1,32,64); s2 += __shfl_xor(s2,32,64);
  q0 += __shfl_xor(q0,32,64); q1 += __shfl_xor(q1,32,64); q2 += __shfl_xor(q2,32,64);
  mn0 = fminf(mn0, __shfl_xor(mn0,32,64));
  mn1 = fminf(mn1, __shfl_xor(mn1,32,64));
  mn2 = fminf(mn2, __shfl_xor(mn2,32,64));
  mx0 = fmaxf(mx0, __shfl_xor(mx0,32,64));
  mx1 = fmaxf(mx1, __shfl_xor(mx1,32,64));
  mx2 = fmaxf(mx2, __shfl_xor(mx2,32,64));

  float dc = (float)(d>0?d:1);
  float inv = 1.0f/dc;
  float m0=s0*inv, m1=s1*inv, m2=s2*inv;
  float sd0 = sqrtf(fmaxf(q0*inv - m0*m0, 0.0f) + 1e-5f);
  float sd1 = sqrtf(fmaxf(q1*inv - m1*m1, 0.0f) + 1e-5f);
  float sd2 = sqrtf(fmaxf(q2*inv - m2*m2, 0.0f) + 1e-5f);
  if(d==0){ mn0=mn1=mn2=0.0f; mx0=mx1=mx2=0.0f; }

  unsigned* zr32 = (unsigned*)(Z + (size_t)g*KZ);
  unsigned short* zr = (unsigned short*)zr32;
  if(h == 0){
    zr32[t]       = packbf(m0, m1);
    zr32[48 + t]  = packbf(mn0, mn1);
    zr32[96 + t]  = packbf(mx0, mx1);
    zr32[144 + t] = packbf(sd0, sd1);
    zr[64 + t]        = f2bf(m2);
    zr[96 + 64 + t]   = f2bf(mn2);
    zr[192 + 64 + t]  = f2bf(mx2);
    zr[288 + 64 + t]  = f2bf(sd2);
  } else {
    const unsigned* xg32 = (const unsigned*)(xpb + (size_t)g*DD);
    zr32[192 + t] = (d>0) ? xg32[t] : 0u;
    if(t < 8)  zr32[224 + t] = (d>0) ? xg32[32 + t] : 0u;
    if(t >= 8 && t < 16) zr32[232 + (t-8)] = (t==8) ? 0x3F80u : 0u;
  }
  if(lane == 0){
    float logd = logf(dc + 1.0f);
    sc[g] = make_float2(logd/AVG_LD, AVG_LD/logd);
  }
}

// LDS-free GEMM, BM=64: 782 blocks (3/CU) for latency hiding; 1 m-tile per wave.
__global__ __launch_bounds__(256) void k_gemm(
    const unsigned short* __restrict__ Z, const unsigned short* __restrict__ WcT,
    const float2* __restrict__ sc, const float* __restrict__ bias,
    float* __restrict__ outb, float* __restrict__ stats){
  __shared__ float sred[4][160];
  int tid = threadIdx.x;
  int wave = tid >> 6, lane = tid & 63;
  int r = lane & 15, q = lane >> 4;
  int m0 = blockIdx.x*64 + wave*16;
  const unsigned short* Ap = Z + (size_t)(m0 + r)*KZ + q*8;
  const unsigned short* Bp = WcT + (size_t)r*KZ + q*8;
  f32x4 acc[15];
  #pragma unroll
  for(int i=0;i<15;++i) acc[i] = (f32x4){0.f,0.f,0.f,0.f};
  #pragma unroll 1
  for(int k0=0; k0<KZ; k0+=32){
    bf16x8 a = *(const bf16x8*)(Ap + k0);
    #pragma unroll
    for(int ct=0; ct<15; ++ct){
      bf16x8 b = *(const bf16x8*)(Bp + (size_t)ct*16*KZ + k0);
      acc[ct] = __builtin_amdgcn_mfma_f32_16x16x32_bf16(a, b, acc[ct], 0, 0, 0);
    }
  }
  float colS[5], colQ[5];
  #pragma unroll
  for(int ct=0; ct<5; ++ct){ colS[ct]=0.f; colQ[ct]=0.f; }
  #pragma unroll
  for(int rr=0; rr<4; ++rr){
    int grow = m0 + q*4 + rr;
    if(grow < NN){
      float2 ab = sc[grow];
      #pragma unroll
      for(int ct=0; ct<5; ++ct){
        int c = ct*16 + r;
        float v = acc[ct][rr] + ab.x*acc[ct+5][rr] + ab.y*acc[ct+10][rr] + bias[c];
        outb[(size_t)grow*DD + c] = v;
        colS[ct] += v; colQ[ct] += v*v;
      }
    }
  }
  #pragma unroll
  for(int ct=0; ct<5; ++ct){
    colS[ct] += __shfl_xor(colS[ct], 16, 64);
    colS[ct] += __shfl_xor(colS[ct], 32, 64);
    colQ[ct] += __shfl_xor(colQ[ct], 16, 64);
    colQ[ct] += __shfl_xor(colQ[ct], 32, 64);
  }
  if(q == 0){
    #pragma unroll
    for(int ct=0; ct<5; ++ct){
      int c = ct*16 + r;
      sred[wave][c] = colS[ct];
      sred[wave][80+c] = colQ[ct];
    }
  }
  __syncthreads();
  if(tid < 160){
    atomicAdd(&stats[tid], sred[0][tid] + sred[1][tid] + sred[2][tid] + sred[3][tid]);
  }
}

// BN-finalize + BN-apply + relu + residual + next-layer xp.
__global__ __launch_bounds__(256) void k_apply(
    const float* __restrict__ outb, const float* __restrict__ stats,
    const float* __restrict__ g_, const float* __restrict__ b_,
    const float* __restrict__ xc, float* __restrict__ xn,
    const unsigned short* __restrict__ pe_all, unsigned short* __restrict__ xpb,
    int lnext, int do_xp){
  __shared__ float murs[160];
  int tid = threadIdx.x;
  if(tid < 80){
    float mu = stats[tid] / (float)NN;
    float var = stats[80+tid] / (float)NN - mu*mu;
    murs[tid] = mu;
    murs[80+tid] = rsqrtf(var + 1e-5f);
  }
  __syncthreads();
  int idx = blockIdx.x*blockDim.x + tid;
  if(idx >= NN*20) return;
  int c = (idx % 20) * 4;
  float4 o = ((const float4*)outb)[idx];
  float4 x = ((const float4*)xc)[idx];
  float4 r;
  r.x = fmaxf((o.x - murs[c+0])*murs[80+c+0]*g_[c+0] + b_[c+0], 0.0f) + x.x;
  r.y = fmaxf((o.y - murs[c+1])*murs[80+c+1]*g_[c+1] + b_[c+1], 0.0f) + x.y;
  r.z = fmaxf((o.z - murs[c+2])*murs[80+c+2]*g_[c+2] + b_[c+2], 0.0f) + x.z;
  r.w = fmaxf((o.w - murs[c+3])*murs[80+c+3]*g_[c+3] + b_[c+3], 0.0f) + x.w;
  ((float4*)xn)[idx] = r;
  if(do_xp){
    int i = idx / 20;
    uint2 pe = ((const uint2*)pe_all)[(size_t)i*(NPE/4) + lnext*(DD/4) + (idx % 20)];
    float p0 = bf2f((unsigned short)(pe.x & 0xffffu));
    float p1 = bf2f((unsigned short)(pe.x >> 16));
    float p2 = bf2f((unsigned short)(pe.y & 0xffffu));
    float p3 = bf2f((unsigned short)(pe.y >> 16));
    uint2 out;
    out.x = packbf(r.x + p0, r.y + p1);
    out.y = packbf(r.z + p2, r.w + p3);
    ((uint2*)xpb)[idx] = out;
  }
}

// ---------------- head (pool + MLP fused; one block per graph) ----------------
__device__ __forceinline__ int lbound(const int* b, int n, int v){
  int lo=0, hi=n;
  while(lo < hi){ int mid = (lo+hi)>>1; if(b[mid] < v) lo = mid+1; else hi = mid; }
  return lo;
}

__global__ __launch_bounds__(640) void k_poolmlp(
    const float* __restrict__ xf, const int* __restrict__ batch,
    const float* __restrict__ w1, const float* __restrict__ b1,
    const float* __restrict__ w2, const float* __restrict__ b2,
    const float* __restrict__ w3, const float* __restrict__ b3,
    float* __restrict__ out){
  __shared__ float red[8][80];
  __shared__ float pooled[80];
  __shared__ float h1[40], h2[20];
  int g = blockIdx.x;
  int tid = threadIdx.x;
  int stripe = tid / 80, c = tid % 80;
  int lo = lbound(batch, NN, g), hi = lbound(batch, NN, g+1);
  float s = 0.0f;
  for(int i = lo + stripe; i < hi; i += 8) s += xf[(size_t)i*DD + c];
  red[stripe][c] = s;
  __syncthreads();
  if(tid < 80){
    float tsum = 0.0f;
    #pragma unroll
    for(int k=0;k<8;++k) tsum += red[k][tid];
    int cnt = hi - lo;
    pooled[tid] = tsum / (float)(cnt > 0 ? cnt : 1);
  }
  __syncthreads();
  if(tid < 40){
    float h = b1[tid];
    for(int cc=0; cc<80; ++cc) h += pooled[cc] * w1[cc*40 + tid];
    h1[tid] = fmaxf(h, 0.0f);
  }
  __syncthreads();
  if(tid < 20){
    float h = b2[tid];
    for(int cc=0; cc<40; ++cc) h += h1[cc] * w2[cc*20 + tid];
    h2[tid] = fmaxf(h, 0.0f);
  }
  __syncthreads();
  if(tid == 0){
    float o = b3[0];
    for(int j=0;j<20;++j) o += h2[j] * w3[j];
    out[g] = o;
  }
}

// ---------------- launch ----------------
extern "C" void kernel_launch(void* const* d_in, const int* in_sizes, int n_in,
                              void* d_out, int out_size, void* d_ws, size_t ws_size,
                              hipStream_t stream){
  const float* x0     = (const float*)d_in[0];
  const int*   ei     = (const int*)d_in[1];
  const float* ea     = (const float*)d_in[2];
  const float* PE     = (const float*)d_in[3];
  const int*   batch  = (const int*)d_in[5];
  const float* pe_w   = (const float*)d_in[6];
  const float* pe_b   = (const float*)d_in[7];
  const float* conv_w = (const float*)d_in[8];
  const float* conv_b = (const float*)d_in[9];
  const float* bn_g   = (const float*)d_in[10];
  const float* bn_b   = (const float*)d_in[11];
  const float* w1 = (const float*)d_in[12];
  const float* b1 = (const float*)d_in[13];
  const float* w2 = (const float*)d_in[14];
  const float* b2 = (const float*)d_in[15];
  const float* w3 = (const float*)d_in[16];
  const float* b3 = (const float*)d_in[17];
  float* dout = (float*)d_out;

  char* p = (char*)d_ws;
  auto alloc = [&](size_t bytes)->char*{
    char* r = p; p += (bytes + 255) & ~(size_t)255; return r;
  };
  int* deg  = (int*)alloc((size_t)NN*4 + (size_t)NLAY*160*4);   // deg + stats contiguous
  float* stats4 = (float*)(deg + NN);
  int* pos  = (int*)alloc((size_t)NN*4);
  int* off  = (int*)alloc((size_t)(NN+1)*4);
  int* bsum = (int*)alloc((size_t)NB*4);
  unsigned short* erec = (unsigned short*)alloc((size_t)NE*EREC*2);
  unsigned short* xpb  = (unsigned short*)alloc((size_t)NN*DD*2);
  unsigned short* PEb  = (unsigned short*)alloc((size_t)MPAD*KP*2);
  unsigned short* pwT  = (unsigned short*)alloc((size_t)NPE*KP*2);
  unsigned short* pe_all = (unsigned short*)alloc((size_t)MPAD*NPE*2);
  unsigned short* Z    = (unsigned short*)alloc((size_t)MPAD*KZ*2);
  unsigned short* WcT  = (unsigned short*)alloc((size_t)NLAY*NOUT*KZ*2);
  float* outb = (float*)alloc((size_t)NN*DD*4);
  float* xA   = (float*)alloc((size_t)NN*DD*4);
  float* xB   = (float*)alloc((size_t)NN*DD*4);
  float2* sc  = (float2*)alloc((size_t)MPAD*8);

  hipMemsetAsync(deg, 0, (size_t)NN*4 + (size_t)NLAY*160*4, stream);
  k_init<<<(R_TOT+255)/256, 256, 0, stream>>>(ei, deg, Z, conv_w, WcT, PE, pe_w, pe_b,
                                              PEb, pwT);
  k_pegemm<<<MPAD/64, 256, 0, stream>>>(PEb, pwT, x0, pe_all, xpb);
  k_scan1<<<NB, 256, 0, stream>>>(deg, bsum);
  k_scan3<<<NB, 256, 0, stream>>>(deg, bsum, off, pos);
  k_fill<<<(NE+255)/256, 256, 0, stream>>>(ei, ea, pos, erec);

  const float* xc = x0;
  float* bufs[2] = {xA, xB};
  for(int l=0; l<NLAY; ++l){
    float* xn = bufs[l & 1];
    float* stats = stats4 + l*160;
    k_agg<<<(NN+3)/4, 256, 0, stream>>>(xpb, erec, off, Z, sc);
    k_gemm<<<NBLK, 256, 0, stream>>>(Z, WcT + (size_t)l*NOUT*KZ, sc, conv_b + l*DD,
                                     outb, stats);
    int do_xp = (l < NLAY-1) ? 1 : 0;
    int lnext = (l+1 < NLAY) ? l+1 : 0;
    k_apply<<<(NN*20+255)/256, 256, 0, stream>>>(outb, stats, bn_g + l*DD, bn_b + l*DD,
                                                 xc, xn, pe_all, xpb, lnext, do_xp);
    xc = xn;
  }
  k_poolmlp<<<NG, 640, 0, stream>>>(xc, batch, w1, b1, w2, b2, w3, b3, dout);
}

// Round 17
// 586.939 us; speedup vs baseline: 1.7702x; 1.7702x over previous
//
#include <hip/hip_runtime.h>
#include <stdint.h>

#define NN 50000
#define DD 80
#define NE 800000
#define EDIM 16
#define PED 37
#define NG 256
#define NLAY 4
#define KZ 480
#define NOUT 240
#define MPAD 50048
#define NBLK (MPAD/128)
#define NB 196
#define KP 64
#define NPE (NLAY*DD)   // 320
#define EREC 32         // edge record: 32 ushorts = 64B
#define AVG_LD 1.4059212841460147f
#define S5 0.0031622776601683794f

typedef __bf16 bf16x8 __attribute__((ext_vector_type(8)));
typedef float f32x4 __attribute__((ext_vector_type(4)));

__device__ __forceinline__ unsigned short f2bf(float f){
  union { float f; unsigned u; } v; v.f = f;
  return (unsigned short)((v.u + 0x7fffu + ((v.u >> 16) & 1u)) >> 16);
}
__device__ __forceinline__ float bf2f(unsigned short u){
  union { unsigned u; float f; } v; v.u = ((unsigned)u) << 16; return v.f;
}
__device__ __forceinline__ unsigned packbf(float a, float b){
  return (unsigned)f2bf(a) | ((unsigned)f2bf(b) << 16);
}

// ---- fused init: hist, Z-pad=0 (uint4), wprep (4 layers), PEb bf16, pwT bf16 ----
#define R_HIST NE
#define R_ZP8  (((MPAD-NN)*KZ)/8)
#define R_WP   (NLAY*NOUT*KZ)
#define R_PEB  (MPAD*KP)
#define R_PWT  (NPE*KP)
#define R_TOT  (R_HIST + R_ZP8 + R_WP + R_PEB + R_PWT)

__global__ void k_init(const int* __restrict__ ei, int* deg, unsigned short* Z,
                       const float* __restrict__ conv_w, unsigned short* __restrict__ WcT,
                       const float* __restrict__ PE,
                       const float* __restrict__ pe_w, const float* __restrict__ pe_b,
                       unsigned short* __restrict__ PEb, unsigned short* __restrict__ pwT){
  int idx = blockIdx.x*blockDim.x + threadIdx.x;
  if(idx < R_HIST){ atomicAdd(&deg[ei[NE + idx]], 1); return; }
  int r1 = idx - R_HIST;
  if(r1 < R_ZP8){
    uint4* zp = (uint4*)(Z + (size_t)NN*KZ);
    zp[r1] = (uint4){0,0,0,0};
    return;
  }
  int r2 = r1 - R_ZP8;
  if(r2 < R_WP){
    int l = r2 / (NOUT*KZ);
    int k = r2 % (NOUT*KZ);
    int j = k / KZ;
    int r = k % KZ;
    int ks = j / DD, c = j % DD;
    const float* cw = conv_w + (size_t)l*2112*DD;
    float val = 0.0f;
    if(r < 384){
      int stat = r/96, m = r%96;
      val = cw[(size_t)(ks*704 + stat*176 + 80 + m)*DD + c];
    } else if(r < 464){
      int m = r - 384;
      int b = ks*704 + m;
      val = cw[(size_t)b*DD + c] + cw[(size_t)(b+176)*DD + c] + cw[(size_t)(b+352)*DD + c];
    } else if(r == 464){
      float s = 0.0f; int b = ks*704 + 528;
      for(int m=0;m<80;++m) s += cw[(size_t)(b+m)*DD + c];
      val = S5 * s;
    }
    WcT[(size_t)l*NOUT*KZ + k] = f2bf(val);
    return;
  }
  int r3 = r2 - R_WP;
  if(r3 < R_PEB){
    int i = r3 / KP, k = r3 % KP;
    float v = 0.0f;
    if(i < NN){
      if(k < PED) v = PE[(size_t)i*PED + k];
      else if(k == PED) v = 1.0f;
    }
    PEb[r3] = f2bf(v);
    return;
  }
  int r4 = r3 - R_PEB;
  if(r4 < R_PWT){
    int j = r4 / KP, k = r4 % KP;
    int l = j / DD, c = j % DD;
    float v = 0.0f;
    if(k < PED) v = pe_w[(size_t)(l*PED + k)*DD + c];
    else if(k == PED) v = pe_b[l*DD + c];
    pwT[r4] = f2bf(v);
  }
}

// PE-embedding GEMM
__global__ __launch_bounds__(256) void k_pegemm(
    const unsigned short* __restrict__ PEb, const unsigned short* __restrict__ pwT,
    const float* __restrict__ x0, unsigned short* __restrict__ pe_all,
    unsigned short* __restrict__ xpb){
  int tid = threadIdx.x;
  int wave = tid >> 6, lane = tid & 63;
  int r = lane & 15, q = lane >> 4;
  int m0 = blockIdx.x*64 + wave*16;
  const unsigned short* Ap = PEb + (size_t)(m0 + r)*KP + q*8;
  const unsigned short* Bp = pwT + (size_t)r*KP + q*8;
  f32x4 acc[20];
  #pragma unroll
  for(int i=0;i<20;++i) acc[i] = (f32x4){0.f,0.f,0.f,0.f};
  #pragma unroll
  for(int k0=0; k0<KP; k0+=32){
    bf16x8 a = *(const bf16x8*)(Ap + k0);
    #pragma unroll
    for(int ct=0; ct<20; ++ct){
      bf16x8 b = *(const bf16x8*)(Bp + (size_t)ct*16*KP + k0);
      acc[ct] = __builtin_amdgcn_mfma_f32_16x16x32_bf16(a, b, acc[ct], 0, 0, 0);
    }
  }
  #pragma unroll
  for(int rr=0; rr<4; ++rr){
    int grow = m0 + q*4 + rr;
    #pragma unroll
    for(int ct=0; ct<20; ++ct){
      int c = ct*16 + r;
      float v = acc[ct][rr];
      pe_all[(size_t)grow*NPE + c] = f2bf(v);
      if(c < DD && grow < NN)
        xpb[(size_t)grow*DD + c] = f2bf(x0[(size_t)grow*DD + c] + v);
    }
  }
}

// ---------------- CSR build ----------------
__global__ void k_scan1(const int* __restrict__ deg, int* bsum){
  __shared__ int red[256];
  int i = blockIdx.x*256 + threadIdx.x;
  int v = (i < NN) ? deg[i] : 0;
  red[threadIdx.x] = v; __syncthreads();
  for(int d=128; d>0; d>>=1){
    if(threadIdx.x < d) red[threadIdx.x] += red[threadIdx.x + d];
    __syncthreads();
  }
  if(threadIdx.x == 0) bsum[blockIdx.x] = red[0];
}

// merged scan: each block reduces bsum[0..blockIdx) itself, then local scan
__global__ void k_scan3(const int* __restrict__ deg, const int* __restrict__ bsum,
                        int* off, int* pos){
  __shared__ int s[256];
  __shared__ int base_sh;
  int t = threadIdx.x;
  int v = (t < blockIdx.x) ? bsum[t] : 0;   // NB=196 < 256
  s[t] = v; __syncthreads();
  for(int d=128; d>0; d>>=1){
    if(t < d) s[t] += s[t + d];
    __syncthreads();
  }
  if(t == 0) base_sh = s[0];
  __syncthreads();
  int base = base_sh;
  __syncthreads();
  int i = blockIdx.x*256 + t;
  int dv = (i < NN) ? deg[i] : 0;
  s[t] = dv; __syncthreads();
  for(int d=1; d<256; d<<=1){
    int u = (t >= d) ? s[t-d] : 0;
    __syncthreads();
    s[t] += u;
    __syncthreads();
  }
  int excl = s[t] - dv + base;
  if(i < NN){ off[i] = excl; pos[i] = excl; }
  if(blockIdx.x == NB-1 && t == 255) off[NN] = s[255] + base;
}

// fill CSR: one full 64B record per edge [16 bf16 ea | src int | pad]
__global__ void k_fill(const int* __restrict__ ei, const float* __restrict__ ea,
                       int* pos, unsigned short* __restrict__ erec){
  int e = blockIdx.x*blockDim.x + threadIdx.x;
  if(e >= NE) return;
  int t = ei[NE + e];
  int idx = atomicAdd(&pos[t], 1);
  const float4* s = (const float4*)(ea + (size_t)e*EDIM);
  float4 f0=s[0], f1=s[1], f2=s[2], f3=s[3];
  unsigned short tmp[32];
  tmp[0]=f2bf(f0.x); tmp[1]=f2bf(f0.y); tmp[2]=f2bf(f0.z); tmp[3]=f2bf(f0.w);
  tmp[4]=f2bf(f1.x); tmp[5]=f2bf(f1.y); tmp[6]=f2bf(f1.z); tmp[7]=f2bf(f1.w);
  tmp[8]=f2bf(f2.x); tmp[9]=f2bf(f2.y); tmp[10]=f2bf(f2.z); tmp[11]=f2bf(f2.w);
  tmp[12]=f2bf(f3.x); tmp[13]=f2bf(f3.y); tmp[14]=f2bf(f3.z); tmp[15]=f2bf(f3.w);
  *(int*)&tmp[16] = ei[e];
  *(int*)&tmp[18] = 0;
  *(uint4*)&tmp[20] = (uint4){0,0,0,0};
  *(uint4*)&tmp[28] = (uint4){0,0,0,0};
  uint4* d = (uint4*)(erec + (size_t)idx*EREC);
  d[0] = *(uint4*)&tmp[0];
  d[1] = *(uint4*)&tmp[8];
  d[2] = *(uint4*)&tmp[16];
  d[3] = *(uint4*)&tmp[24];
}

// ---------------- per-layer aggregation [R12-proven] ----------------
__global__ __launch_bounds__(256) void k_agg(
    const unsigned short* __restrict__ xpb, const unsigned short* __restrict__ erec,
    const int* __restrict__ off, unsigned short* __restrict__ Z,
    float2* __restrict__ sc){
  int g = blockIdx.x*4 + (threadIdx.x >> 6);
  if(g >= NN) return;
  int lane = threadIdx.x & 63;
  int h = lane >> 5, t = lane & 31;
  int lo = off[g], hi = off[g+1];
  int d = hi - lo;
  float s0=0,s1=0,s2=0,q0=0,q1=0,q2=0;
  const float INF = __builtin_huge_valf();
  float mn0=INF,mn1=INF,mn2=INF,mx0=-INF,mx1=-INF,mx2=-INF;

  auto edge = [&](int j){
    const unsigned short* er = erec + (size_t)j*EREC;
    int sr = *(const int*)(er + 16);
    const unsigned* xr32 = (const unsigned*)(xpb + (size_t)sr*DD);
    unsigned w = xr32[t];
    union {unsigned u; float f;} ua, ub;
    ua.u = w << 16; ub.u = w & 0xffff0000u;
    float v0 = ua.f, v1 = ub.f;
    unsigned short u2 = (t < 16) ? xpb[(size_t)sr*DD + 64 + t] : er[t - 16];
    float v2 = bf2f(u2);
    s0+=v0; q0+=v0*v0; mn0=fminf(mn0,v0); mx0=fmaxf(mx0,v0);
    s1+=v1; q1+=v1*v1; mn1=fminf(mn1,v1); mx1=fmaxf(mx1,v1);
    s2+=v2; q2+=v2*v2; mn2=fminf(mn2,v2); mx2=fmaxf(mx2,v2);
  };
  int j = lo + h;
  for(; j + 2 < hi; j += 4){ edge(j); edge(j+2); }
  if(j < hi) edge(j);

  s0 += __shfl_xor(s0,32,64); s1 += __shfl_xor(s1,32,64); s2 += __shfl_xor(s2,32,64);
  q0 += __shfl_xor(q0,32,64); q1 += __shfl_xor(q1,32,64); q2 += __shfl_xor(q2,32,64);
  mn0 = fminf(mn0, __shfl_xor(mn0,32,64));
  mn1 = fminf(mn1, __shfl_xor(mn1,32,64));
  mn2 = fminf(mn2, __shfl_xor(mn2,32,64));
  mx0 = fmaxf(mx0, __shfl_xor(mx0,32,64));
  mx1 = fmaxf(mx1, __shfl_xor(mx1,32,64));
  mx2 = fmaxf(mx2, __shfl_xor(mx2,32,64));

  float dc = (float)(d>0?d:1);
  float inv = 1.0f/dc;
  float m0=s0*inv, m1=s1*inv, m2=s2*inv;
  float sd0 = sqrtf(fmaxf(q0*inv - m0*m0, 0.0f) + 1e-5f);
  float sd1 = sqrtf(fmaxf(q1*inv - m1*m1, 0.0f) + 1e-5f);
  float sd2 = sqrtf(fmaxf(q2*inv - m2*m2, 0.0f) + 1e-5f);
  if(d==0){ mn0=mn1=mn2=0.0f; mx0=mx1=mx2=0.0f; }

  unsigned* zr32 = (unsigned*)(Z + (size_t)g*KZ);
  unsigned short* zr = (unsigned short*)zr32;
  if(h == 0){
    zr32[t]       = packbf(m0, m1);
    zr32[48 + t]  = packbf(mn0, mn1);
    zr32[96 + t]  = packbf(mx0, mx1);
    zr32[144 + t] = packbf(sd0, sd1);
    zr[64 + t]        = f2bf(m2);
    zr[96 + 64 + t]   = f2bf(mn2);
    zr[192 + 64 + t]  = f2bf(mx2);
    zr[288 + 64 + t]  = f2bf(sd2);
  } else {
    const unsigned* xg32 = (const unsigned*)(xpb + (size_t)g*DD);
    zr32[192 + t] = (d>0) ? xg32[t] : 0u;
    if(t < 8)  zr32[224 + t] = (d>0) ? xg32[32 + t] : 0u;
    if(t >= 8 && t < 16) zr32[232 + (t-8)] = (t==8) ? 0x3F80u : 0u;
  }
  if(lane == 0){
    float logd = logf(dc + 1.0f);
    sc[g] = make_float2(logd/AVG_LD, AVG_LD/logd);
  }
}

// LDS-free GEMM BM=128 [R12-proven]; BN partial sums via atomicAdd.
__global__ __launch_bounds__(256) void k_gemm(
    const unsigned short* __restrict__ Z, const unsigned short* __restrict__ WcT,
    const float2* __restrict__ sc, const float* __restrict__ bias,
    float* __restrict__ outb, float* __restrict__ stats){
  __shared__ float sred[4][160];
  int tid = threadIdx.x;
  int wave = tid >> 6, lane = tid & 63;
  int r = lane & 15, q = lane >> 4;
  int m0 = blockIdx.x*128 + wave*32;
  const unsigned short* Ap = Z + (size_t)(m0 + r)*KZ + q*8;
  const unsigned short* Bp = WcT + (size_t)r*KZ + q*8;
  f32x4 acc0[15], acc1[15];
  #pragma unroll
  for(int i=0;i<15;++i){ acc0[i]=(f32x4){0.f,0.f,0.f,0.f}; acc1[i]=(f32x4){0.f,0.f,0.f,0.f}; }
  #pragma unroll 1
  for(int k0=0; k0<KZ; k0+=32){
    bf16x8 a0 = *(const bf16x8*)(Ap + k0);
    bf16x8 a1 = *(const bf16x8*)(Ap + 16*KZ + k0);
    #pragma unroll
    for(int ct=0; ct<15; ++ct){
      bf16x8 b = *(const bf16x8*)(Bp + (size_t)ct*16*KZ + k0);
      acc0[ct] = __builtin_amdgcn_mfma_f32_16x16x32_bf16(a0, b, acc0[ct], 0, 0, 0);
      acc1[ct] = __builtin_amdgcn_mfma_f32_16x16x32_bf16(a1, b, acc1[ct], 0, 0, 0);
    }
  }
  float colS[5], colQ[5];
  #pragma unroll
  for(int ct=0; ct<5; ++ct){ colS[ct]=0.f; colQ[ct]=0.f; }
  #pragma unroll
  for(int rr=0; rr<4; ++rr){
    int grow = m0 + q*4 + rr;
    if(grow < NN){
      float2 ab = sc[grow];
      #pragma unroll
      for(int ct=0; ct<5; ++ct){
        int c = ct*16 + r;
        float v = acc0[ct][rr] + ab.x*acc0[ct+5][rr] + ab.y*acc0[ct+10][rr] + bias[c];
        outb[(size_t)grow*DD + c] = v;
        colS[ct] += v; colQ[ct] += v*v;
      }
    }
  }
  #pragma unroll
  for(int rr=0; rr<4; ++rr){
    int grow = m0 + 16 + q*4 + rr;
    if(grow < NN){
      float2 ab = sc[grow];
      #pragma unroll
      for(int ct=0; ct<5; ++ct){
        int c = ct*16 + r;
        float v = acc1[ct][rr] + ab.x*acc1[ct+5][rr] + ab.y*acc1[ct+10][rr] + bias[c];
        outb[(size_t)grow*DD + c] = v;
        colS[ct] += v; colQ[ct] += v*v;
      }
    }
  }
  #pragma unroll
  for(int ct=0; ct<5; ++ct){
    colS[ct] += __shfl_xor(colS[ct], 16, 64);
    colS[ct] += __shfl_xor(colS[ct], 32, 64);
    colQ[ct] += __shfl_xor(colQ[ct], 16, 64);
    colQ[ct] += __shfl_xor(colQ[ct], 32, 64);
  }
  if(q == 0){
    #pragma unroll
    for(int ct=0; ct<5; ++ct){
      int c = ct*16 + r;
      sred[wave][c] = colS[ct];
      sred[wave][80+c] = colQ[ct];
    }
  }
  __syncthreads();
  if(tid < 160){
    atomicAdd(&stats[tid], sred[0][tid] + sred[1][tid] + sred[2][tid] + sred[3][tid]);
  }
}

// BN-finalize + BN-apply + relu + residual + next-layer xp.
__global__ __launch_bounds__(256) void k_apply(
    const float* __restrict__ outb, const float* __restrict__ stats,
    const float* __restrict__ g_, const float* __restrict__ b_,
    const float* __restrict__ xc, float* __restrict__ xn,
    const unsigned short* __restrict__ pe_all, unsigned short* __restrict__ xpb,
    int lnext, int do_xp){
  __shared__ float murs[160];
  int tid = threadIdx.x;
  if(tid < 80){
    float mu = stats[tid] / (float)NN;
    float var = stats[80+tid] / (float)NN - mu*mu;
    murs[tid] = mu;
    murs[80+tid] = rsqrtf(var + 1e-5f);
  }
  __syncthreads();
  int idx = blockIdx.x*blockDim.x + tid;
  if(idx >= NN*20) return;
  int c = (idx % 20) * 4;
  float4 o = ((const float4*)outb)[idx];
  float4 x = ((const float4*)xc)[idx];
  float4 r;
  r.x = fmaxf((o.x - murs[c+0])*murs[80+c+0]*g_[c+0] + b_[c+0], 0.0f) + x.x;
  r.y = fmaxf((o.y - murs[c+1])*murs[80+c+1]*g_[c+1] + b_[c+1], 0.0f) + x.y;
  r.z = fmaxf((o.z - murs[c+2])*murs[80+c+2]*g_[c+2] + b_[c+2], 0.0f) + x.z;
  r.w = fmaxf((o.w - murs[c+3])*murs[80+c+3]*g_[c+3] + b_[c+3], 0.0f) + x.w;
  ((float4*)xn)[idx] = r;
  if(do_xp){
    int i = idx / 20;
    uint2 pe = ((const uint2*)pe_all)[(size_t)i*(NPE/4) + lnext*(DD/4) + (idx % 20)];
    float p0 = bf2f((unsigned short)(pe.x & 0xffffu));
    float p1 = bf2f((unsigned short)(pe.x >> 16));
    float p2 = bf2f((unsigned short)(pe.y & 0xffffu));
    float p3 = bf2f((unsigned short)(pe.y >> 16));
    uint2 out;
    out.x = packbf(r.x + p0, r.y + p1);
    out.y = packbf(r.z + p2, r.w + p3);
    ((uint2*)xpb)[idx] = out;
  }
}

// ---------------- head (pool + MLP fused; one block per graph) ----------------
__device__ __forceinline__ int lbound(const int* b, int n, int v){
  int lo=0, hi=n;
  while(lo < hi){ int mid = (lo+hi)>>1; if(b[mid] < v) lo = mid+1; else hi = mid; }
  return lo;
}

__global__ __launch_bounds__(640) void k_poolmlp(
    const float* __restrict__ xf, const int* __restrict__ batch,
    const float* __restrict__ w1, const float* __restrict__ b1,
    const float* __restrict__ w2, const float* __restrict__ b2,
    const float* __restrict__ w3, const float* __restrict__ b3,
    float* __restrict__ out){
  __shared__ float red[8][80];
  __shared__ float pooled[80];
  __shared__ float h1[40], h2[20];
  int g = blockIdx.x;
  int tid = threadIdx.x;
  int stripe = tid / 80, c = tid % 80;
  int lo = lbound(batch, NN, g), hi = lbound(batch, NN, g+1);
  float s = 0.0f;
  for(int i = lo + stripe; i < hi; i += 8) s += xf[(size_t)i*DD + c];
  red[stripe][c] = s;
  __syncthreads();
  if(tid < 80){
    float tsum = 0.0f;
    #pragma unroll
    for(int k=0;k<8;++k) tsum += red[k][tid];
    int cnt = hi - lo;
    pooled[tid] = tsum / (float)(cnt > 0 ? cnt : 1);
  }
  __syncthreads();
  if(tid < 40){
    float h = b1[tid];
    for(int cc=0; cc<80; ++cc) h += pooled[cc] * w1[cc*40 + tid];
    h1[tid] = fmaxf(h, 0.0f);
  }
  __syncthreads();
  if(tid < 20){
    float h = b2[tid];
    for(int cc=0; cc<40; ++cc) h += h1[cc] * w2[cc*20 + tid];
    h2[tid] = fmaxf(h, 0.0f);
  }
  __syncthreads();
  if(tid == 0){
    float o = b3[0];
    for(int j=0;j<20;++j) o += h2[j] * w3[j];
    out[g] = o;
  }
}

// ---------------- launch ----------------
extern "C" void kernel_launch(void* const* d_in, const int* in_sizes, int n_in,
                              void* d_out, int out_size, void* d_ws, size_t ws_size,
                              hipStream_t stream){
  const float* x0     = (const float*)d_in[0];
  const int*   ei     = (const int*)d_in[1];
  const float* ea     = (const float*)d_in[2];
  const float* PE     = (const float*)d_in[3];
  const int*   batch  = (const int*)d_in[5];
  const float* pe_w   = (const float*)d_in[6];
  const float* pe_b   = (const float*)d_in[7];
  const float* conv_w = (const float*)d_in[8];
  const float* conv_b = (const float*)d_in[9];
  const float* bn_g   = (const float*)d_in[10];
  const float* bn_b   = (const float*)d_in[11];
  const float* w1 = (const float*)d_in[12];
  const float* b1 = (const float*)d_in[13];
  const float* w2 = (const float*)d_in[14];
  const float* b2 = (const float*)d_in[15];
  const float* w3 = (const float*)d_in[16];
  const float* b3 = (const float*)d_in[17];
  float* dout = (float*)d_out;

  char* p = (char*)d_ws;
  auto alloc = [&](size_t bytes)->char*{
    char* r = p; p += (bytes + 255) & ~(size_t)255; return r;
  };
  int* deg  = (int*)alloc((size_t)NN*4 + (size_t)NLAY*160*4);   // deg + stats contiguous
  float* stats4 = (float*)(deg + NN);
  int* pos  = (int*)alloc((size_t)NN*4);
  int* off  = (int*)alloc((size_t)(NN+1)*4);
  int* bsum = (int*)alloc((size_t)NB*4);
  unsigned short* erec = (unsigned short*)alloc((size_t)NE*EREC*2);
  unsigned short* xpb  = (unsigned short*)alloc((size_t)NN*DD*2);
  unsigned short* PEb  = (unsigned short*)alloc((size_t)MPAD*KP*2);
  unsigned short* pwT  = (unsigned short*)alloc((size_t)NPE*KP*2);
  unsigned short* pe_all = (unsigned short*)alloc((size_t)MPAD*NPE*2);
  unsigned short* Z    = (unsigned short*)alloc((size_t)MPAD*KZ*2);
  unsigned short* WcT  = (unsigned short*)alloc((size_t)NLAY*NOUT*KZ*2);
  float* outb = (float*)alloc((size_t)NN*DD*4);
  float* xA   = (float*)alloc((size_t)NN*DD*4);
  float* xB   = (float*)alloc((size_t)NN*DD*4);
  float2* sc  = (float2*)alloc((size_t)MPAD*8);

  hipMemsetAsync(deg, 0, (size_t)NN*4 + (size_t)NLAY*160*4, stream);
  k_init<<<(R_TOT+255)/256, 256, 0, stream>>>(ei, deg, Z, conv_w, WcT, PE, pe_w, pe_b,
                                              PEb, pwT);
  k_pegemm<<<MPAD/64, 256, 0, stream>>>(PEb, pwT, x0, pe_all, xpb);
  k_scan1<<<NB, 256, 0, stream>>>(deg, bsum);
  k_scan3<<<NB, 256, 0, stream>>>(deg, bsum, off, pos);
  k_fill<<<(NE+255)/256, 256, 0, stream>>>(ei, ea, pos, erec);

  const float* xc = x0;
  float* bufs[2] = {xA, xB};
  for(int l=0; l<NLAY; ++l){
    float* xn = bufs[l & 1];
    float* stats = stats4 + l*160;
    k_agg<<<(NN+3)/4, 256, 0, stream>>>(xpb, erec, off, Z, sc);
    k_gemm<<<NBLK, 256, 0, stream>>>(Z, WcT + (size_t)l*NOUT*KZ, sc, conv_b + l*DD,
                                     outb, stats);
    int do_xp = (l < NLAY-1) ? 1 : 0;
    int lnext = (l+1 < NLAY) ? l+1 : 0;
    k_apply<<<(NN*20+255)/256, 256, 0, stream>>>(outb, stats, bn_g + l*DD, bn_b + l*DD,
                                                 xc, xn, pe_all, xpb, lnext, do_xp);
    xc = xn;
  }
  k_poolmlp<<<NG, 640, 0, stream>>>(xc, batch, w1, b1, w2, b2, w3, b3, dout);
}